// Round 1
// baseline (226.993 us; speedup 1.0000x reference)
//
#include <hip/hip_runtime.h>
#include <hip/hip_bf16.h>

// loss = (1/C) * sum_i log( sum_j exp(<x_i,x_j>/T) ),  x: [16384, 256] fp32, rows unit-norm.
// Strategy: bf16 MFMA GEMM (X * X^T) fused with exp + row-sum; log+reduce in a tiny kernel.

#define N_ROWS 16384
#define KD     256          // inner dim
#define BM     128          // rows per block
#define BN     64           // cols per B tile
#define NSPLIT 4            // column splits (grid = 128 * 4 = 512 blocks)
#define COLS_PER (N_ROWS / NSPLIT)   // 4096
#define NITER    (COLS_PER / BN)     // 64

// exp(sim/T) = exp2( dot * (1/T)*log2(e) ),  T = 0.5
#define EXP_SCALE 2.88539008177792681f

typedef short short8 __attribute__((ext_vector_type(8)));   // 8 bf16 = 4 VGPRs
typedef float f32x4  __attribute__((ext_vector_type(4)));

typedef __attribute__((address_space(3))) void       lds_void;
typedef const __attribute__((address_space(1))) void gm_void;

__device__ __forceinline__ float fast_exp2(float x) {
#if __has_builtin(__builtin_amdgcn_exp2f)
    return __builtin_amdgcn_exp2f(x);
#else
    return exp2f(x);
#endif
}

// async global->LDS, 16B per lane; dst must be wave-uniform base (HW adds lane*16)
__device__ __forceinline__ void gll16(const void* g, void* l) {
    __builtin_amdgcn_global_load_lds((gm_void*)g, (lds_void*)l, 16, 0, 0);
}

// LDS layout: row-major [row][512B] with 16B-chunk XOR swizzle to kill the
// stride-512B bank conflict on ds_read_b128 (G4 / T2). byte = row*512 + (x ^ ((row&7)<<4))
__device__ __forceinline__ int swz(int row, int xbyte) {
    return (row << 9) + (xbyte ^ ((row & 7) << 4));
}

// ---------------- fp32 -> bf16 (RNE) ----------------
__global__ void convert_kernel(const float* __restrict__ x, unsigned short* __restrict__ xb) {
    int i = (blockIdx.x * 256 + threadIdx.x) * 4;
    float4 v = *(const float4*)(x + i);
    ushort4 o;
    {
        unsigned int u;
        u = __float_as_uint(v.x); u += 0x7fff + ((u >> 16) & 1); o.x = (unsigned short)(u >> 16);
        u = __float_as_uint(v.y); u += 0x7fff + ((u >> 16) & 1); o.y = (unsigned short)(u >> 16);
        u = __float_as_uint(v.z); u += 0x7fff + ((u >> 16) & 1); o.z = (unsigned short)(u >> 16);
        u = __float_as_uint(v.w); u += 0x7fff + ((u >> 16) & 1); o.w = (unsigned short)(u >> 16);
    }
    *(ushort4*)(xb + i) = o;
}

// ---------------- main fused kernel ----------------
// Block: 512 threads = 8 waves; wave w owns A rows [r0 + w*16, +16), A frags in registers.
// Loop over this split's 4096 columns in BN=64 tiles, B double-buffered in LDS (2x32KB).
__global__ __launch_bounds__(512, 2)
void simloss_main(const unsigned short* __restrict__ xb, float* __restrict__ partial) {
    __shared__ __align__(128) char smem[65536];   // A staging (64KB) then B dbuf (2x32KB)

    const int tid  = threadIdx.x;
    const int lane = tid & 63;
    const int w    = tid >> 6;
    const int bx   = blockIdx.x;
    const int split   = bx & (NSPLIT - 1);
    const int rb      = bx >> 2;                 // log2(NSPLIT) = 2
    const int r0      = rb * BM;
    const int colBase = split * COLS_PER;

    // ---- stage A tile (128 rows x 512B = 64KB) swizzled: linear LDS dest,
    //      inverse-swizzled global source (rule #21) ----
    #pragma unroll
    for (int g = 0; g < 8; ++g) {
        int chunk = g * 512 + w * 64 + lane;     // 16B chunk index, 4096 total
        int row   = chunk >> 5;                  // 32 chunks per row
        int kc    = chunk & 31;
        int srcE  = (r0 + row) * KD + ((((kc * 16) ^ ((row & 7) << 4))) >> 1);
        gll16(xb + srcE, smem + (g * 512 + w * 64) * 16);
    }
    asm volatile("s_waitcnt vmcnt(0)" ::: "memory");
    __syncthreads();

    // ---- A fragments to registers: wave's 16 rows x K=256 = 8 frags x 8 bf16/lane ----
    // mfma_f32_16x16x32_bf16 A-layout: row = lane&15, k = kt*32 + (lane>>4)*8 + j
    short8 afrag[8];
    {
        const int arow = w * 16 + (lane & 15);
        const int kb   = (lane >> 4) * 16;       // byte offset of 8-bf16 group in 64B k-step
        #pragma unroll
        for (int kt = 0; kt < 8; ++kt)
            afrag[kt] = *(const short8*)(smem + swz(arow, kt * 64 + kb));
    }
    __syncthreads();   // all waves done reading A; smem now reusable for B

    float rowsum[4] = {0.f, 0.f, 0.f, 0.f};

    auto stageB = [&](int buf, int j0) {
        #pragma unroll
        for (int g = 0; g < 4; ++g) {
            int chunk = (w * 4 + g) * 64 + lane;  // 2048 chunks (64 rows x 32)
            int row   = chunk >> 5;
            int kc    = chunk & 31;
            int srcE  = (j0 + row) * KD + ((((kc * 16) ^ ((row & 7) << 4))) >> 1);
            gll16(xb + srcE, smem + buf * 32768 + ((w * 4 + g) * 64) * 16);
        }
    };

    stageB(0, colBase);

    const int lrow15 = lane & 15;
    const int kb     = (lane >> 4) * 16;

    for (int it = 0; it < NITER; ++it) {
        const int cur = it & 1;
        __syncthreads();    // drains vmcnt -> buf[cur] staged; all waves done with buf[cur^1]
        if (it + 1 < NITER) stageB(cur ^ 1, colBase + (it + 1) * BN);

        const char* bbase = smem + cur * 32768;
        #pragma unroll
        for (int ct = 0; ct < 4; ++ct) {
            const int brow = ct * 16 + lrow15;    // B col = lane&15 within 16-col subtile
            f32x4 acc = {0.f, 0.f, 0.f, 0.f};
            #pragma unroll
            for (int kt = 0; kt < 8; ++kt) {
                short8 bfrag = *(const short8*)(bbase + swz(brow, kt * 64 + kb));
                acc = __builtin_amdgcn_mfma_f32_16x16x32_bf16(afrag[kt], bfrag, acc, 0, 0, 0);
            }
            // C/D layout (HW-verified): col = lane&15, row = (lane>>4)*4 + r
            #pragma unroll
            for (int r = 0; r < 4; ++r)
                rowsum[r] += fast_exp2(acc[r] * EXP_SCALE);
        }
    }

    // ---- reduce each row over the 16 column-lanes, write per-split partial ----
    #pragma unroll
    for (int r = 0; r < 4; ++r) {
        float v = rowsum[r];
        v += __shfl_xor(v, 1);
        v += __shfl_xor(v, 2);
        v += __shfl_xor(v, 4);
        v += __shfl_xor(v, 8);
        if (lrow15 == 0) {
            int row = r0 + w * 16 + (lane >> 4) * 4 + r;
            partial[split * N_ROWS + row] = v;
        }
    }
}

// ---------------- finalize: loss = sum_i log(rowsum_i) / 100 ----------------
__global__ void finalize_kernel(const float* __restrict__ partial, float* __restrict__ out) {
    __shared__ float red[256];
    float acc = 0.f;
    for (int i = threadIdx.x; i < N_ROWS; i += 256) {
        float s = partial[i] + partial[N_ROWS + i] + partial[2 * N_ROWS + i] + partial[3 * N_ROWS + i];
        acc += logf(s);
    }
    red[threadIdx.x] = acc;
    __syncthreads();
    for (int s = 128; s > 0; s >>= 1) {
        if (threadIdx.x < s) red[threadIdx.x] += red[threadIdx.x + s];
        __syncthreads();
    }
    if (threadIdx.x == 0) out[0] = red[0] * 0.01f;
}

extern "C" void kernel_launch(void* const* d_in, const int* in_sizes, int n_in,
                              void* d_out, int out_size, void* d_ws, size_t ws_size,
                              hipStream_t stream) {
    const float* x = (const float*)d_in[0];
    unsigned short* xb = (unsigned short*)d_ws;                              // 8 MB bf16
    float* partial = (float*)((char*)d_ws + (size_t)N_ROWS * KD * 2);        // 4*16384 f32
    float* out = (float*)d_out;

    convert_kernel<<<(N_ROWS * KD) / (256 * 4), 256, 0, stream>>>(x, xb);
    simloss_main<<<(N_ROWS / BM) * NSPLIT, 512, 0, stream>>>(xb, partial);
    finalize_kernel<<<1, 256, 0, stream>>>(partial, out);
}

// Round 2
// 222.759 us; speedup vs baseline: 1.0190x; 1.0190x over previous
//
#include <hip/hip_runtime.h>
#include <hip/hip_bf16.h>

// loss = (1/C) * sum_i log( sum_j exp(<x_i,x_j>/T) ),  x: [16384, 256] fp32, unit rows.
// bf16 MFMA GEMM (X X^T) fused with exp2 + row-sum; log+reduce in a tiny kernel.
//
// R1 restructure: wave owns 64 M-rows (A fully in registers, 4 MFMAs per B-frag read);
// B staged FRAGMENT-MAJOR in LDS (1KB per MFMA fragment, lane-linear ds_read_b128 ->
// zero bank conflicts by construction; per-lane-permuted global src, linear LDS dst).

#define N_ROWS 16384
#define KD     256
#define BM     256                    // 4 waves x 64 rows
#define BN     64
#define NSPLIT 8                      // grid = 64 row-blocks * 8 = 512 = 2 blocks/CU
#define COLS_PER (N_ROWS / NSPLIT)    // 2048
#define NITER    (COLS_PER / BN)      // 32

// exp(sim/T) = exp2( dot * (1/T)*log2(e) ), T = 0.5
#define EXP_SCALE 2.88539008177792681f

typedef short short8 __attribute__((ext_vector_type(8)));   // 8 bf16 = 4 VGPRs
typedef float f32x4  __attribute__((ext_vector_type(4)));

typedef __attribute__((address_space(3))) void       lds_void;
typedef const __attribute__((address_space(1))) void gm_void;

__device__ __forceinline__ float fast_exp2(float x) {
#if __has_builtin(__builtin_amdgcn_exp2f)
    return __builtin_amdgcn_exp2f(x);
#else
    return exp2f(x);
#endif
}

// async global->LDS, 16B/lane; LDS dst wave-uniform base (HW adds lane*16)
__device__ __forceinline__ void gll16(const void* g, void* l) {
    __builtin_amdgcn_global_load_lds((gm_void*)g, (lds_void*)l, 16, 0, 0);
}

// ---------------- fp32 -> bf16 (RNE) ----------------
__global__ void convert_kernel(const float* __restrict__ x, unsigned short* __restrict__ xb) {
    int i = (blockIdx.x * 256 + threadIdx.x) * 4;
    float4 v = *(const float4*)(x + i);
    ushort4 o;
    {
        unsigned int u;
        u = __float_as_uint(v.x); u += 0x7fff + ((u >> 16) & 1); o.x = (unsigned short)(u >> 16);
        u = __float_as_uint(v.y); u += 0x7fff + ((u >> 16) & 1); o.y = (unsigned short)(u >> 16);
        u = __float_as_uint(v.z); u += 0x7fff + ((u >> 16) & 1); o.z = (unsigned short)(u >> 16);
        u = __float_as_uint(v.w); u += 0x7fff + ((u >> 16) & 1); o.w = (unsigned short)(u >> 16);
    }
    *(ushort4*)(xb + i) = o;
}

// ---------------- main fused kernel ----------------
// 256 thr = 4 waves. Wave w: A rows [r0 + w*64, +64) in registers (afrag[4][8]).
// B tile (64 cols x K=256) double-buffered in LDS, fragment-major:
//   frag f = ct*8 + kt  at bytes [f*1024, f*1024+1024), lane slot = lane*16.
//   B-frag layout (mfma_16x16x32): col = lane&15 (tile row j0+ct*16+(lane&15)),
//   k-bytes = kt*64 + (lane>>4)*16.
__global__ __launch_bounds__(256, 2)
void simloss_main(const unsigned short* __restrict__ xb, float* __restrict__ partial) {
    __shared__ __align__(128) char smem[65536];   // 2 x 32KB B double-buffer

    const int tid  = threadIdx.x;
    const int lane = tid & 63;
    const int w    = tid >> 6;                    // 0..3
    const int bx   = blockIdx.x;
    // XCD = bx%8 (dispatch round-robin): give each XCD ONE column split so all
    // 64 blocks on an XCD stream an identical B sequence (L2-hot).
    const int split = bx & 7;
    const int rb    = bx >> 3;                    // 0..63
    const int r0      = rb * BM;
    const int colBase = split * COLS_PER;

    const int l15 = lane & 15;
    const int lg  = lane >> 4;                    // 0..3

    // ---- A fragments straight from global (one-time, L2/L3-resident) ----
    // A-layout (mfma_16x16x32): row = lane&15, k = kt*32 + (lane>>4)*8 + j
    short8 afrag[4][8];
    #pragma unroll
    for (int m = 0; m < 4; ++m) {
        const unsigned short* arow = xb + (size_t)(r0 + w * 64 + m * 16 + l15) * KD + lg * 8;
        #pragma unroll
        for (int kt = 0; kt < 8; ++kt)
            afrag[m][kt] = *(const short8*)(arow + kt * 32);
    }

    // ---- B staging: wave w stages frags ct=w, kt=0..7 (8 gll16 per tile) ----
    // per-lane global src: row = j0 + w*16 + (lane&15), elem = kt*32 + (lane>>4)*8
    const unsigned short* bsrc0 = xb + (size_t)(colBase + w * 16 + l15) * KD + lg * 8;
    char* const ldst0 = smem + (w * 8) * 1024;

    auto stageB = [&](int buf, int it2) {
        const unsigned short* s = bsrc0 + (size_t)it2 * (BN * KD);
        char* dst = ldst0 + buf * 32768;
        #pragma unroll
        for (int kt = 0; kt < 8; ++kt)
            gll16(s + kt * 32, dst + kt * 1024);
    };

    float rowsum[4][4] = {{0.f}};

    stageB(0, 0);

    for (int it = 0; it < NITER; ++it) {
        const int cur = it & 1;
        if (it + 1 < NITER) {
            stageB(cur ^ 1, it + 1);                         // next tile in flight
            asm volatile("s_waitcnt vmcnt(8)" ::: "memory"); // cur's 8 done, next's 8 pending
        } else {
            asm volatile("s_waitcnt vmcnt(0)" ::: "memory");
        }
        __builtin_amdgcn_s_barrier();                        // all waves' cur-frags visible
        asm volatile("" ::: "memory");

        const char* bbase = smem + cur * 32768;
        #pragma unroll
        for (int ct = 0; ct < 4; ++ct) {
            short8 bfrag[8];
            #pragma unroll
            for (int kt = 0; kt < 8; ++kt)                   // lane-linear: zero conflicts
                bfrag[kt] = *(const short8*)(bbase + (ct * 8 + kt) * 1024 + lane * 16);
            f32x4 acc[4];
            #pragma unroll
            for (int m = 0; m < 4; ++m) acc[m] = (f32x4){0.f, 0.f, 0.f, 0.f};
            #pragma unroll
            for (int kt = 0; kt < 8; ++kt)                   // kt outer: 4 indep acc chains
                #pragma unroll
                for (int m = 0; m < 4; ++m)
                    acc[m] = __builtin_amdgcn_mfma_f32_16x16x32_bf16(afrag[m][kt], bfrag[kt], acc[m], 0, 0, 0);
            // C/D: col = lane&15, row-in-16 = (lane>>4)*4 + r
            #pragma unroll
            for (int m = 0; m < 4; ++m)
                #pragma unroll
                for (int r = 0; r < 4; ++r)
                    rowsum[m][r] += fast_exp2(acc[m][r] * EXP_SCALE);
        }

        asm volatile("" ::: "memory");
        __builtin_amdgcn_s_barrier();                        // all waves done reading buf[cur]
        asm volatile("" ::: "memory");
    }

    // ---- reduce over the 16 column-lanes, write per-split partial row sums ----
    #pragma unroll
    for (int m = 0; m < 4; ++m)
        #pragma unroll
        for (int r = 0; r < 4; ++r) {
            float v = rowsum[m][r];
            v += __shfl_xor(v, 1);
            v += __shfl_xor(v, 2);
            v += __shfl_xor(v, 4);
            v += __shfl_xor(v, 8);
            if (l15 == 0) {
                int row = r0 + w * 64 + m * 16 + lg * 4 + r;
                partial[split * N_ROWS + row] = v;
            }
        }
}

// ---------------- finalize: loss = sum_i log(rowsum_i) / 100 ----------------
__global__ void finalize_kernel(const float* __restrict__ partial, float* __restrict__ out) {
    __shared__ float red[256];
    float acc = 0.f;
    for (int i = threadIdx.x; i < N_ROWS; i += 256) {
        float s = 0.f;
        #pragma unroll
        for (int p = 0; p < NSPLIT; ++p) s += partial[p * N_ROWS + i];
        acc += logf(s);
    }
    red[threadIdx.x] = acc;
    __syncthreads();
    for (int s = 128; s > 0; s >>= 1) {
        if (threadIdx.x < s) red[threadIdx.x] += red[threadIdx.x + s];
        __syncthreads();
    }
    if (threadIdx.x == 0) out[0] = red[0] * 0.01f;
}

extern "C" void kernel_launch(void* const* d_in, const int* in_sizes, int n_in,
                              void* d_out, int out_size, void* d_ws, size_t ws_size,
                              hipStream_t stream) {
    const float* x = (const float*)d_in[0];
    unsigned short* xb = (unsigned short*)d_ws;                           // 8 MB bf16
    float* partial = (float*)((char*)d_ws + (size_t)N_ROWS * KD * 2);     // 8*16384 f32
    float* out = (float*)d_out;

    convert_kernel<<<(N_ROWS * KD) / (256 * 4), 256, 0, stream>>>(x, xb);
    simloss_main<<<(N_ROWS / BM) * NSPLIT, 256, 0, stream>>>(xb, partial);
    finalize_kernel<<<1, 256, 0, stream>>>(partial, out);
}

// Round 3
// 171.359 us; speedup vs baseline: 1.3247x; 1.2999x over previous
//
#include <hip/hip_runtime.h>
#include <hip/hip_bf16.h>

// loss = (1/C) * sum_i log( sum_j exp(<x_i,x_j>/T) ),  x: [16384, 256] fp32, unit rows.
// bf16 MFMA GEMM (X X^T) fused with exp2 + row-sum; parallel log+reduce finalize.
//
// R2: (a) pin A-fragments in VGPRs via asm (R1's compiler rematerialized them ->
// 34.8 GB of A re-fetch); (b) fold 1/T*log2(e) into the bf16 conversion as sqrt(scale)
// on BOTH operands (kills the per-element v_mul); (c) parallel finalize (was ~100us
// on one CU).

#define N_ROWS 16384
#define KD     256
#define BM     256                    // 4 waves x 64 rows
#define BN     64
#define NSPLIT 8                      // grid = 64 row-blocks * 8 = 512 = 2 blocks/CU
#define COLS_PER (N_ROWS / NSPLIT)    // 2048
#define NITER    (COLS_PER / BN)      // 32

// exp(sim/T) = exp2( dot * (1/T)*log2(e) );  scale folded as sqrt into both operands:
// xb = bf16( x * sqrt(2.88539008177792681) )  ->  acc = sim * 2.88539...
#define SCALE_SQRT 1.6986436f

typedef short short8 __attribute__((ext_vector_type(8)));   // 8 bf16 = 4 VGPRs
typedef float f32x4  __attribute__((ext_vector_type(4)));

typedef __attribute__((address_space(3))) void       lds_void;
typedef const __attribute__((address_space(1))) void gm_void;

__device__ __forceinline__ float fast_exp2(float x) {
#if __has_builtin(__builtin_amdgcn_exp2f)
    return __builtin_amdgcn_exp2f(x);
#else
    return exp2f(x);
#endif
}

// async global->LDS, 16B/lane; LDS dst wave-uniform base (HW adds lane*16)
__device__ __forceinline__ void gll16(const void* g, void* l) {
    __builtin_amdgcn_global_load_lds((gm_void*)g, (lds_void*)l, 16, 0, 0);
}

// ---------------- fp32 -> bf16 (RNE), pre-scaled by sqrt(1/T * log2 e) ----------------
__global__ void convert_kernel(const float* __restrict__ x, unsigned short* __restrict__ xb) {
    int i = (blockIdx.x * 256 + threadIdx.x) * 4;
    float4 v = *(const float4*)(x + i);
    ushort4 o;
    {
        unsigned int u;
        u = __float_as_uint(v.x * SCALE_SQRT); u += 0x7fff + ((u >> 16) & 1); o.x = (unsigned short)(u >> 16);
        u = __float_as_uint(v.y * SCALE_SQRT); u += 0x7fff + ((u >> 16) & 1); o.y = (unsigned short)(u >> 16);
        u = __float_as_uint(v.z * SCALE_SQRT); u += 0x7fff + ((u >> 16) & 1); o.z = (unsigned short)(u >> 16);
        u = __float_as_uint(v.w * SCALE_SQRT); u += 0x7fff + ((u >> 16) & 1); o.w = (unsigned short)(u >> 16);
    }
    *(ushort4*)(xb + i) = o;
}

// ---------------- main fused kernel ----------------
// 256 thr = 4 waves. Wave w: A rows [r0 + w*64, +64) pinned in registers (afrag[4][8]).
// B tile (64 cols x K=256) double-buffered in LDS, fragment-major (1KB per MFMA frag,
// lane-linear ds_read_b128 -> zero bank conflicts; per-lane-permuted global src).
__global__ __launch_bounds__(256, 2)
void simloss_main(const unsigned short* __restrict__ xb, float* __restrict__ partial) {
    __shared__ __align__(128) char smem[65536];   // 2 x 32KB B double-buffer

    const int tid  = threadIdx.x;
    const int lane = tid & 63;
    const int w    = tid >> 6;                    // 0..3
    const int bx   = blockIdx.x;
    const int split = bx & 7;                     // XCD k (bx%8) -> one column split
    const int rb    = bx >> 3;                    // 0..63
    const int r0      = rb * BM;
    const int colBase = split * COLS_PER;

    const int l15 = lane & 15;
    const int lg  = lane >> 4;                    // 0..3

    // ---- A fragments from global (L2-resident), then PIN in VGPRs ----
    // A-layout (mfma_16x16x32): row = lane&15, k = kt*32 + (lane>>4)*8 + j
    short8 afrag[4][8];
    #pragma unroll
    for (int m = 0; m < 4; ++m) {
        const unsigned short* arow = xb + (size_t)(r0 + w * 64 + m * 16 + l15) * KD + lg * 8;
        #pragma unroll
        for (int kt = 0; kt < 8; ++kt)
            afrag[m][kt] = *(const short8*)(arow + kt * 32);
    }
    #pragma unroll
    for (int m = 0; m < 4; ++m)
        #pragma unroll
        for (int kt = 0; kt < 8; ++kt)
            asm volatile("" : "+v"(afrag[m][kt]));   // forbid rematerialization/reload

    // ---- B staging: wave w stages frags (ct=w, kt=0..7): 8 gll16 per tile ----
    const unsigned short* bsrc0 = xb + (size_t)(colBase + w * 16 + l15) * KD + lg * 8;
    char* const ldst0 = smem + (w * 8) * 1024;

    auto stageB = [&](int buf, int it2) {
        const unsigned short* s = bsrc0 + (size_t)it2 * (BN * KD);
        char* dst = ldst0 + buf * 32768;
        #pragma unroll
        for (int kt = 0; kt < 8; ++kt)
            gll16(s + kt * 32, dst + kt * 1024);
    };

    float rowsum[4][4] = {{0.f}};

    stageB(0, 0);

    for (int it = 0; it < NITER; ++it) {
        const int cur = it & 1;
        if (it + 1 < NITER) {
            stageB(cur ^ 1, it + 1);                         // next tile in flight
            asm volatile("s_waitcnt vmcnt(8)" ::: "memory"); // cur's 8 landed
        } else {
            asm volatile("s_waitcnt vmcnt(0)" ::: "memory");
        }
        __builtin_amdgcn_s_barrier();
        asm volatile("" ::: "memory");

        const char* bbase = smem + cur * 32768;
        #pragma unroll
        for (int ct = 0; ct < 4; ++ct) {
            short8 bfrag[8];
            #pragma unroll
            for (int kt = 0; kt < 8; ++kt)                   // lane-linear: zero conflicts
                bfrag[kt] = *(const short8*)(bbase + (ct * 8 + kt) * 1024 + lane * 16);
            f32x4 acc[4];
            #pragma unroll
            for (int m = 0; m < 4; ++m) acc[m] = (f32x4){0.f, 0.f, 0.f, 0.f};
            #pragma unroll
            for (int kt = 0; kt < 8; ++kt)
                #pragma unroll
                for (int m = 0; m < 4; ++m)
                    acc[m] = __builtin_amdgcn_mfma_f32_16x16x32_bf16(afrag[m][kt], bfrag[kt], acc[m], 0, 0, 0);
            // C/D: col = lane&15, row-in-16 = (lane>>4)*4 + r ; scale pre-folded
            #pragma unroll
            for (int m = 0; m < 4; ++m)
                #pragma unroll
                for (int r = 0; r < 4; ++r)
                    rowsum[m][r] += fast_exp2(acc[m][r]);
        }

        asm volatile("" ::: "memory");
        __builtin_amdgcn_s_barrier();
        asm volatile("" ::: "memory");
    }

    // ---- reduce over the 16 column-lanes, write per-split partial row sums ----
    #pragma unroll
    for (int m = 0; m < 4; ++m)
        #pragma unroll
        for (int r = 0; r < 4; ++r) {
            float v = rowsum[m][r];
            v += __shfl_xor(v, 1);
            v += __shfl_xor(v, 2);
            v += __shfl_xor(v, 4);
            v += __shfl_xor(v, 8);
            if (l15 == 0) {
                int row = r0 + w * 64 + m * 16 + lg * 4 + r;
                partial[split * N_ROWS + row] = v;
            }
        }
}

// ---------------- finalize: loss = sum_i log(rowsum_i) / 100 (parallel) ----------------
__global__ void zero_out(float* __restrict__ out) { out[0] = 0.f; }

__global__ void finalize_kernel(const float* __restrict__ partial, float* __restrict__ out) {
    int i = blockIdx.x * 256 + threadIdx.x;      // one row per thread, 64 blocks
    float s = 0.f;
    #pragma unroll
    for (int p = 0; p < NSPLIT; ++p) s += partial[p * N_ROWS + i];
    float v = logf(s);
    #pragma unroll
    for (int off = 1; off < 64; off <<= 1) v += __shfl_xor(v, off);
    __shared__ float red[4];
    if ((threadIdx.x & 63) == 0) red[threadIdx.x >> 6] = v;
    __syncthreads();
    if (threadIdx.x == 0)
        atomicAdd(out, (red[0] + red[1] + red[2] + red[3]) * 0.01f);
}

extern "C" void kernel_launch(void* const* d_in, const int* in_sizes, int n_in,
                              void* d_out, int out_size, void* d_ws, size_t ws_size,
                              hipStream_t stream) {
    const float* x = (const float*)d_in[0];
    unsigned short* xb = (unsigned short*)d_ws;                           // 8 MB bf16 (pre-scaled)
    float* partial = (float*)((char*)d_ws + (size_t)N_ROWS * KD * 2);     // 8*16384 f32
    float* out = (float*)d_out;

    convert_kernel<<<(N_ROWS * KD) / (256 * 4), 256, 0, stream>>>(x, xb);
    simloss_main<<<(N_ROWS / BM) * NSPLIT, 256, 0, stream>>>(xb, partial);
    zero_out<<<1, 1, 0, stream>>>(out);
    finalize_kernel<<<N_ROWS / 256, 256, 0, stream>>>(partial, out);
}